// Round 3
// baseline (9134.315 us; speedup 1.0000x reference)
//
#include <hip/hip_runtime.h>

#define N_NODES 50000
#define N_EDGES 1600000

// weight offsets (in floats) inside the converted-weights region of d_ws
#define O_ENCW0 0
#define O_ENCB0 108
#define O_ENCW1 126
#define O_ENCB1 450
#define O_ENCW2 468
#define O_ENCB2 756
#define O_EDGEW0 772
#define O_EDGEB0 13572
#define O_EDGEW1 13652
#define O_EDGEB1 14932
#define O_NODEW0 14948
#define O_NODEB0 19428
#define O_NODEW1 19484
#define O_NODEB1 21276
#define W_TOTAL 21308

__device__ __forceinline__ float bf2f(unsigned int u) {
    return __uint_as_float(u << 16);
}
__device__ __forceinline__ unsigned short f2bf(float f) {
    unsigned int u = __float_as_uint(f);
    u += 0x7fffu + ((u >> 16) & 1u);   // RNE (finite values only here)
    return (unsigned short)(u >> 16);
}
__device__ __forceinline__ float lrelu(float x) { return x > 0.f ? x : 0.01f * x; }

struct WPack {
    const void* p[14];
    int off[15];
};

// ---- detect flags: [0] = edge_index is int64, [1] = floats are f32 ----
// int64: high (odd int32) words of edge_index all zero.
// f32: reading x (random normals) as u16 halves shows wild exponent fields
//      (low-mantissa halves of f32s); bf16 data has all exponents in [90,160].
__global__ void detect_flags(const unsigned int* __restrict__ xw,
                             const int* __restrict__ eidx,
                             int* __restrict__ flags) {
    int t = threadIdx.x;  // 64 threads
    int v = eidx[2 * t + 1];
    unsigned long long bi = __ballot(v != 0);
    int insane = 0;
    for (int i = 0; i < 64; i++) {
        unsigned int w = xw[t * 64 + i];   // first 16 KB of x: safe for either dtype
        unsigned int l = w & 0xffffu, h = w >> 16;
        unsigned int el = (l >> 7) & 0xffu, eh = (h >> 7) & 0xffu;
        if ((l & 0x7fffu) != 0u && (el < 90u || el > 160u)) insane++;
        if ((h & 0x7fffu) != 0u && (eh < 90u || eh > 160u)) insane++;
    }
    unsigned long long bf = __ballot(insane > 8);
    if (t == 0) {
        flags[0] = (bi == 0ull) ? 1 : 0;
        flags[1] = (bf != 0ull) ? 1 : 0;
    }
}

__device__ __forceinline__ void load_rc(const int* eidx, int flag64, int e, int& r, int& c) {
    if (flag64) {
        const long long* e64 = (const long long*)eidx;
        r = (int)e64[e];
        c = (int)e64[N_EDGES + e];
    } else {
        r = eidx[e];
        c = eidx[N_EDGES + e];
    }
}

// e-history slot pointer inside d_out (element size depends on dtype)
__device__ __forceinline__ const char* slot_cptr(const void* base, int slot, int f32) {
    return (const char*)base + (size_t)slot * N_EDGES * 16 * (f32 ? 4 : 2);
}

// ---- convert all weight/bias arrays to f32 in ws ----
__global__ void cvt_w(WPack P, float* __restrict__ dst, const int* __restrict__ flags) {
    int f32 = flags[1];
    int a = blockIdx.x;
    int n = P.off[a + 1] - P.off[a];
    float* d = dst + P.off[a];
    if (f32) {
        const float* s = (const float*)P.p[a];
        for (int i = threadIdx.x; i < n; i += 256) d[i] = s[i];
    } else {
        const unsigned short* s = (const unsigned short*)P.p[a];
        for (int i = threadIdx.x; i < n; i += 256) d[i] = bf2f((unsigned int)s[i]);
    }
}

// ---- n0 = lrelu(x); nc = [n0, n0]; zero s, cnt ----
__global__ void __launch_bounds__(256) init_nodes(const void* __restrict__ xv,
                                                  float* __restrict__ nc,
                                                  float* __restrict__ s,
                                                  float* __restrict__ cnt,
                                                  const int* __restrict__ flags) {
    int i = blockIdx.x * 256 + threadIdx.x;
    if (i >= N_NODES) return;
    float f[32];
    if (flags[1]) {
        const float4* xp = (const float4*)((const float*)xv + (size_t)i * 32);
#pragma unroll
        for (int q = 0; q < 8; q++) {
            float4 v = xp[q];
            f[4 * q] = v.x; f[4 * q + 1] = v.y; f[4 * q + 2] = v.z; f[4 * q + 3] = v.w;
        }
    } else {
        const uint4* xp = (const uint4*)((const unsigned short*)xv + (size_t)i * 32);
#pragma unroll
        for (int q = 0; q < 4; q++) {
            uint4 u = xp[q];
            f[8 * q + 0] = bf2f(u.x & 0xffffu); f[8 * q + 1] = bf2f(u.x >> 16);
            f[8 * q + 2] = bf2f(u.y & 0xffffu); f[8 * q + 3] = bf2f(u.y >> 16);
            f[8 * q + 4] = bf2f(u.z & 0xffffu); f[8 * q + 5] = bf2f(u.z >> 16);
            f[8 * q + 6] = bf2f(u.w & 0xffffu); f[8 * q + 7] = bf2f(u.w >> 16);
        }
    }
    float4* ncp = (float4*)(nc + (size_t)i * 64);
#pragma unroll
    for (int q = 0; q < 8; q++) {
        float4 a = make_float4(lrelu(f[4 * q]), lrelu(f[4 * q + 1]),
                               lrelu(f[4 * q + 2]), lrelu(f[4 * q + 3]));
        ncp[q] = a;
        ncp[8 + q] = a;
    }
    float4 z = make_float4(0.f, 0.f, 0.f, 0.f);
    float4* sp = (float4*)(s + (size_t)i * 16);
    sp[0] = z; sp[1] = z; sp[2] = z; sp[3] = z;
    cnt[i] = 0.f;
}

// ---- encoder MLP 6->18->18->16 (lrelu each); e0 -> slot4 of out; count in-degree ----
__global__ void __launch_bounds__(256) encoder(const void* __restrict__ eav,
                                               const int* __restrict__ eidx,
                                               const int* __restrict__ flags,
                                               const float* __restrict__ wsW,
                                               void* __restrict__ outbase,
                                               float* __restrict__ cnt) {
    const int f32 = flags[1];
    int e = blockIdx.x * 256 + threadIdx.x;  // E % 256 == 0
    float a[6];
    if (f32) {
        const float* ap = (const float*)eav + (size_t)e * 6;
#pragma unroll
        for (int k = 0; k < 6; k++) a[k] = ap[k];
    } else {
        const unsigned short* ap = (const unsigned short*)eav + (size_t)e * 6;
#pragma unroll
        for (int k = 0; k < 6; k++) a[k] = bf2f((unsigned int)ap[k]);
    }

    float h1[18];
#pragma unroll
    for (int j = 0; j < 18; j++) h1[j] = wsW[O_ENCB0 + j];
#pragma unroll
    for (int k = 0; k < 6; k++) {
        float v = a[k];
#pragma unroll
        for (int j = 0; j < 18; j++) h1[j] = fmaf(v, wsW[O_ENCW0 + k * 18 + j], h1[j]);
    }
#pragma unroll
    for (int j = 0; j < 18; j++) h1[j] = lrelu(h1[j]);

    float h2[18];
#pragma unroll
    for (int j = 0; j < 18; j++) h2[j] = wsW[O_ENCB1 + j];
#pragma unroll
    for (int k = 0; k < 18; k++) {
        float v = h1[k];
#pragma unroll
        for (int j = 0; j < 18; j++) h2[j] = fmaf(v, wsW[O_ENCW1 + k * 18 + j], h2[j]);
    }
#pragma unroll
    for (int j = 0; j < 18; j++) h2[j] = lrelu(h2[j]);

    float o[16];
#pragma unroll
    for (int j = 0; j < 16; j++) o[j] = wsW[O_ENCB2 + j];
#pragma unroll
    for (int k = 0; k < 18; k++) {
        float v = h2[k];
#pragma unroll
        for (int j = 0; j < 16; j++) o[j] = fmaf(v, wsW[O_ENCW2 + k * 16 + j], o[j]);
    }
#pragma unroll
    for (int j = 0; j < 16; j++) o[j] = lrelu(o[j]);

    char* sp = (char*)slot_cptr(outbase, 4, f32);
    if (f32) {
        float4* ow = (float4*)(sp + (size_t)e * 64);
#pragma unroll
        for (int q = 0; q < 4; q++)
            ow[q] = make_float4(o[4 * q], o[4 * q + 1], o[4 * q + 2], o[4 * q + 3]);
    } else {
        unsigned int pw[8];
#pragma unroll
        for (int q = 0; q < 8; q++)
            pw[q] = (unsigned int)f2bf(o[2 * q]) | ((unsigned int)f2bf(o[2 * q + 1]) << 16);
        uint4* ow = (uint4*)(sp + (size_t)e * 32);
        ow[0] = make_uint4(pw[0], pw[1], pw[2], pw[3]);
        ow[1] = make_uint4(pw[4], pw[5], pw[6], pw[7]);
    }
    int r, cdum;
    load_rc(eidx, flags[0], e, r, cdum);
    atomicAdd(&cnt[r], 1.0f);
}

// ---- edge update: eh=[nc[row],nc[col],e0,eprev] (160) -> 80 (lrelu) -> 16 (lrelu) ----
template <int DO_ATOMICS>
__global__ void __launch_bounds__(64) edge_step(const float* __restrict__ nc,
                                                const void* __restrict__ outbase_c,
                                                int slot_e0, int slot_prev, int slot_cur,
                                                const int* __restrict__ eidx,
                                                const int* __restrict__ flags,
                                                const float* __restrict__ wsW,
                                                float* __restrict__ s,
                                                void* __restrict__ outbase) {
    __shared__ float sl[64 * 65];   // [edge][feat], stride 65 -> 2-way bank alias (free)
    const int lane = threadIdx.x;   // one wave per block; lane == local edge
    const int e = blockIdx.x * 64 + lane;
    const int f32 = flags[1];
    const float* W0 = wsW + O_EDGEW0;
    const float* b0 = wsW + O_EDGEB0;
    const float* W1 = wsW + O_EDGEW1;
    const float* b1 = wsW + O_EDGEB1;

    int r, c;
    load_rc(eidx, flags[0], e, r, c);

    float acc[80];
#pragma unroll
    for (int q = 0; q < 20; q++) {
        float4 b = ((const float4*)b0)[q];
        acc[4 * q] = b.x; acc[4 * q + 1] = b.y; acc[4 * q + 2] = b.z; acc[4 * q + 3] = b.w;
    }

#pragma unroll 1
    for (int pass = 0; pass < 2; pass++) {
        int idx = pass ? c : r;
        // cooperative coalesced gather: 64 lanes load one nc row per iteration
#pragma unroll 8
        for (int e2 = 0; e2 < 64; e2++) {
            int node = __shfl(idx, e2, 64);
            sl[e2 * 65 + lane] = nc[(size_t)node * 64 + lane];
        }
        __syncthreads();
        const float* Wp = W0 + (size_t)pass * 64 * 80;
        for (int k = 0; k < 64; k++) {
            float v = sl[lane * 65 + k];
            const float4* w = (const float4*)(Wp + k * 80);
#pragma unroll
            for (int q = 0; q < 20; q++) {
                float4 wv = w[q];
                acc[4 * q]     = fmaf(v, wv.x, acc[4 * q]);
                acc[4 * q + 1] = fmaf(v, wv.y, acc[4 * q + 1]);
                acc[4 * q + 2] = fmaf(v, wv.z, acc[4 * q + 2]);
                acc[4 * q + 3] = fmaf(v, wv.w, acc[4 * q + 3]);
            }
        }
        __syncthreads();
    }

    // stage e0 (k=0..15 of row -> W rows 128..143) and e_prev (k=16..31 -> 144..159)
    const char* p0 = slot_cptr(outbase_c, slot_e0, f32);
    const char* pp = slot_cptr(outbase_c, slot_prev, f32);
    if (f32) {
        const float4* a4 = (const float4*)(p0 + (size_t)e * 64);
        const float4* b4 = (const float4*)(pp + (size_t)e * 64);
#pragma unroll
        for (int q = 0; q < 4; q++) {
            float4 u = a4[q];
            int base = lane * 65 + 4 * q;
            sl[base] = u.x; sl[base + 1] = u.y; sl[base + 2] = u.z; sl[base + 3] = u.w;
        }
#pragma unroll
        for (int q = 0; q < 4; q++) {
            float4 u = b4[q];
            int base = lane * 65 + 16 + 4 * q;
            sl[base] = u.x; sl[base + 1] = u.y; sl[base + 2] = u.z; sl[base + 3] = u.w;
        }
    } else {
        const uint4* a4 = (const uint4*)(p0 + (size_t)e * 32);
        const uint4* b4 = (const uint4*)(pp + (size_t)e * 32);
        uint4 evs[4] = {a4[0], a4[1], b4[0], b4[1]};
#pragma unroll
        for (int q = 0; q < 4; q++) {
            uint4 u = evs[q];
            int base = lane * 65 + 8 * q;
            sl[base + 0] = bf2f(u.x & 0xffffu);
            sl[base + 1] = bf2f(u.x >> 16);
            sl[base + 2] = bf2f(u.y & 0xffffu);
            sl[base + 3] = bf2f(u.y >> 16);
            sl[base + 4] = bf2f(u.z & 0xffffu);
            sl[base + 5] = bf2f(u.z >> 16);
            sl[base + 6] = bf2f(u.w & 0xffffu);
            sl[base + 7] = bf2f(u.w >> 16);
        }
    }
    for (int k = 0; k < 32; k++) {
        float v = sl[lane * 65 + k];
        const float4* w = (const float4*)(W0 + (128 + k) * 80);
#pragma unroll
        for (int q = 0; q < 20; q++) {
            float4 wv = w[q];
            acc[4 * q]     = fmaf(v, wv.x, acc[4 * q]);
            acc[4 * q + 1] = fmaf(v, wv.y, acc[4 * q + 1]);
            acc[4 * q + 2] = fmaf(v, wv.z, acc[4 * q + 2]);
            acc[4 * q + 3] = fmaf(v, wv.w, acc[4 * q + 3]);
        }
    }

    // layer 2: 80 -> 16 (fully unrolled: static acc indices)
    float o[16];
#pragma unroll
    for (int q = 0; q < 4; q++) {
        float4 b = ((const float4*)b1)[q];
        o[4 * q] = b.x; o[4 * q + 1] = b.y; o[4 * q + 2] = b.z; o[4 * q + 3] = b.w;
    }
#pragma unroll
    for (int j = 0; j < 80; j++) {
        float v = lrelu(acc[j]);
        const float4* w = (const float4*)(W1 + j * 16);
#pragma unroll
        for (int q = 0; q < 4; q++) {
            float4 wv = w[q];
            o[4 * q]     = fmaf(v, wv.x, o[4 * q]);
            o[4 * q + 1] = fmaf(v, wv.y, o[4 * q + 1]);
            o[4 * q + 2] = fmaf(v, wv.z, o[4 * q + 2]);
            o[4 * q + 3] = fmaf(v, wv.w, o[4 * q + 3]);
        }
    }
    float act[16];
#pragma unroll
    for (int q = 0; q < 16; q++) act[q] = lrelu(o[q]);

    char* oc = (char*)slot_cptr(outbase, slot_cur, f32);
    if (f32) {
        float4* ow = (float4*)(oc + (size_t)e * 64);
#pragma unroll
        for (int q = 0; q < 4; q++)
            ow[q] = make_float4(act[4 * q], act[4 * q + 1], act[4 * q + 2], act[4 * q + 3]);
    } else {
        unsigned int pw[8];
#pragma unroll
        for (int q = 0; q < 8; q++)
            pw[q] = (unsigned int)f2bf(act[2 * q]) | ((unsigned int)f2bf(act[2 * q + 1]) << 16);
        uint4* ow = (uint4*)(oc + (size_t)e * 32);
        ow[0] = make_uint4(pw[0], pw[1], pw[2], pw[3]);
        ow[1] = make_uint4(pw[4], pw[5], pw[6], pw[7]);
    }
    if (DO_ATOMICS) {
#pragma unroll
        for (int q = 0; q < 16; q++) atomicAdd(&s[(size_t)r * 16 + q], act[q]);
    }
}

// ---- node update: nh=[nc, s/max(cnt,1)] (80) -> 56 (relu) -> 32 (relu); zero s ----
__global__ void __launch_bounds__(64) node_step(float* __restrict__ s,
                                                const float* __restrict__ cnt,
                                                float* __restrict__ nc,
                                                const float* __restrict__ wsW) {
    __shared__ float sl[64 * 81];
    const int l = threadIdx.x;
    const int i = blockIdx.x * 64 + l;
    if (i >= N_NODES) return;
    const float* W0 = wsW + O_NODEW0;
    const float* b0 = wsW + O_NODEB0;
    const float* W1 = wsW + O_NODEW1;
    const float* b1 = wsW + O_NODEB1;

    const float4* ncp = (const float4*)(nc + (size_t)i * 64);
#pragma unroll
    for (int q = 0; q < 16; q++) {
        float4 v = ncp[q];
        int base = l * 81 + 4 * q;
        sl[base] = v.x; sl[base + 1] = v.y; sl[base + 2] = v.z; sl[base + 3] = v.w;
    }
    float inv = 1.0f / fmaxf(cnt[i], 1.0f);
    float4* sp = (float4*)(s + (size_t)i * 16);
    float4 z = make_float4(0.f, 0.f, 0.f, 0.f);
#pragma unroll
    for (int q = 0; q < 4; q++) {
        float4 v = sp[q];
        int base = l * 81 + 64 + 4 * q;
        sl[base] = v.x * inv; sl[base + 1] = v.y * inv;
        sl[base + 2] = v.z * inv; sl[base + 3] = v.w * inv;
        sp[q] = z;  // reset accumulator for the next step
    }

    float h[56];
#pragma unroll
    for (int q = 0; q < 14; q++) {
        float4 b = ((const float4*)b0)[q];
        h[4 * q] = b.x; h[4 * q + 1] = b.y; h[4 * q + 2] = b.z; h[4 * q + 3] = b.w;
    }
    for (int k = 0; k < 80; k++) {
        float v = sl[l * 81 + k];
        const float4* w = (const float4*)(W0 + k * 56);
#pragma unroll
        for (int q = 0; q < 14; q++) {
            float4 wv = w[q];
            h[4 * q]     = fmaf(v, wv.x, h[4 * q]);
            h[4 * q + 1] = fmaf(v, wv.y, h[4 * q + 1]);
            h[4 * q + 2] = fmaf(v, wv.z, h[4 * q + 2]);
            h[4 * q + 3] = fmaf(v, wv.w, h[4 * q + 3]);
        }
    }
#pragma unroll
    for (int j = 0; j < 56; j++) sl[l * 81 + j] = fmaxf(h[j], 0.f);

    float o[32];
#pragma unroll
    for (int q = 0; q < 8; q++) {
        float4 b = ((const float4*)b1)[q];
        o[4 * q] = b.x; o[4 * q + 1] = b.y; o[4 * q + 2] = b.z; o[4 * q + 3] = b.w;
    }
    for (int j = 0; j < 56; j++) {
        float v = sl[l * 81 + j];
        const float4* w = (const float4*)(W1 + j * 32);
#pragma unroll
        for (int q = 0; q < 8; q++) {
            float4 wv = w[q];
            o[4 * q]     = fmaf(v, wv.x, o[4 * q]);
            o[4 * q + 1] = fmaf(v, wv.y, o[4 * q + 1]);
            o[4 * q + 2] = fmaf(v, wv.z, o[4 * q + 2]);
            o[4 * q + 3] = fmaf(v, wv.w, o[4 * q + 3]);
        }
    }
    float4* nout = (float4*)(nc + (size_t)i * 64 + 32);
#pragma unroll
    for (int q = 0; q < 8; q++)
        nout[q] = make_float4(fmaxf(o[4 * q], 0.f), fmaxf(o[4 * q + 1], 0.f),
                              fmaxf(o[4 * q + 2], 0.f), fmaxf(o[4 * q + 3], 0.f));
}

extern "C" void kernel_launch(void* const* d_in, const int* in_sizes, int n_in,
                              void* d_out, int out_size, void* d_ws, size_t ws_size,
                              hipStream_t stream) {
    (void)in_sizes; (void)n_in; (void)out_size;
    const void* x  = d_in[0];
    const int* eidx = (const int*)d_in[1];
    const void* ea = d_in[2];

    // d_ws layout (floats): nc[3.2M] | s[800k] | cnt[50k] | wsW | flags[2]
    const size_t WS_NEEDED = (4050000 + W_TOTAL + 2) * sizeof(float);
    if (ws_size < WS_NEEDED) return;  // refuse to corrupt memory; leaves out==0 signature
    float* wsf = (float*)d_ws;
    float* nc  = wsf;
    float* s   = wsf + 3200000;
    float* cnt = wsf + 4000000;
    float* wsW = wsf + 4050000;
    int* flags = (int*)(wsf + 4050000 + W_TOTAL);

    WPack P;
    static const int offs[15] = {0, 108, 126, 450, 468, 756, 772, 13572, 13652,
                                 14932, 14948, 19428, 19484, 21276, 21308};
    for (int a = 0; a < 14; a++) P.p[a] = d_in[3 + a];
    for (int a = 0; a < 15; a++) P.off[a] = offs[a];

    detect_flags<<<1, 64, 0, stream>>>((const unsigned int*)x, eidx, flags);
    cvt_w<<<14, 256, 0, stream>>>(P, wsW, flags);
    init_nodes<<<196, 256, 0, stream>>>(x, nc, s, cnt, flags);
    encoder<<<N_EDGES / 256, 256, 0, stream>>>(ea, eidx, flags, wsW, d_out, cnt);

    // e-history lives in d_out slots (index j): final out[j] = e_{j+2}
    // t=1: e0(s4)->s0; t=2: s0->s0; t=3: s0->s1; t=4: s1->s2; t=5: s2->s3; t=6: s3->s4
    // every overlap is a same-thread read-before-write on a private slot row
    const int prevs[6] = {4, 0, 0, 1, 2, 3};
    const int curs[6]  = {0, 0, 1, 2, 3, 4};

    for (int t = 1; t <= 6; t++) {
        if (t < 6)
            edge_step<1><<<N_EDGES / 64, 64, 0, stream>>>(nc, d_out, 4, prevs[t - 1],
                                                          curs[t - 1], eidx, flags, wsW,
                                                          s, d_out);
        else
            edge_step<0><<<N_EDGES / 64, 64, 0, stream>>>(nc, d_out, 4, prevs[t - 1],
                                                          curs[t - 1], eidx, flags, wsW,
                                                          s, d_out);
        if (t < 6)
            node_step<<<782, 64, 0, stream>>>(s, cnt, nc, wsW);
    }
}

// Round 8
// 8031.380 us; speedup vs baseline: 1.1373x; 1.1373x over previous
//
#include <hip/hip_runtime.h>

#define N_NODES 50000
#define N_EDGES 1600000

// weight offsets (floats) inside the weights region of d_ws
#define O_ENCW0 0
#define O_ENCB0 108
#define O_ENCW1 126
#define O_ENCB1 450
#define O_ENCW2 468
#define O_ENCB2 756
#define O_EDGEW0 772
#define O_EDGEB0 13572
#define O_EDGEW1 13652
#define O_EDGEB1 14932
#define O_NODEW0 14948
#define O_NODEB0 19428
#define O_NODEW1 19484
#define O_NODEB1 21276
#define W_TOTAL 21308

__device__ __forceinline__ float bf2f(unsigned int u) {
    return __uint_as_float(u << 16);
}
__device__ __forceinline__ unsigned short f2bf(float f) {
    unsigned int u = __float_as_uint(f);
    u += 0x7fffu + ((u >> 16) & 1u);   // RNE (finite values only here)
    return (unsigned short)(u >> 16);
}
__device__ __forceinline__ float lrelu(float x) { return x > 0.f ? x : 0.01f * x; }

struct WPack {
    const float* p[14];
    int off[15];
};

// ---- detect flag: edge_index is int64 (high words of first 64 entries all zero) ----
__global__ void detect_flags(const int* __restrict__ eidx, int* __restrict__ flags) {
    int t = threadIdx.x;  // 64 threads
    int v = eidx[2 * t + 1];
    unsigned long long bi = __ballot(v != 0);
    if (t == 0) flags[0] = (bi == 0ull) ? 1 : 0;
}

__device__ __forceinline__ void load_rc(const int* eidx, int flag64, int e, int& r, int& c) {
    if (flag64) {
        const long long* e64 = (const long long*)eidx;
        r = (int)e64[e];
        c = (int)e64[N_EDGES + e];
    } else {
        r = eidx[e];
        c = eidx[N_EDGES + e];
    }
}
__device__ __forceinline__ int load_r(const int* eidx, int flag64, int e) {
    return flag64 ? (int)((const long long*)eidx)[e] : eidx[e];
}

// ---- copy all f32 weight/bias arrays into contiguous ws region ----
__global__ void copy_w(WPack P, float* __restrict__ dst) {
    int a = blockIdx.x;
    const float* s = P.p[a];
    int n = P.off[a + 1] - P.off[a];
    float* d = dst + P.off[a];
    for (int i = threadIdx.x; i < n; i += 256) d[i] = s[i];
}

// ---- n0 = lrelu(x) (f32 in) stored bf16; ncb = [n0, n0]; zero s, cnt ----
__global__ void __launch_bounds__(256) init_nodes(const float* __restrict__ x,
                                                  unsigned short* __restrict__ ncb,
                                                  float* __restrict__ s,
                                                  float* __restrict__ cnt) {
    int i = blockIdx.x * 256 + threadIdx.x;
    if (i >= N_NODES) return;
    const float4* xin = (const float4*)(x + (size_t)i * 32);  // 8 float4
    uint4* np = (uint4*)(ncb + (size_t)i * 64);
#pragma unroll
    for (int q = 0; q < 4; q++) {
        float4 a = xin[2 * q];
        float4 b = xin[2 * q + 1];
        unsigned int w0 = (unsigned int)f2bf(lrelu(a.x)) | ((unsigned int)f2bf(lrelu(a.y)) << 16);
        unsigned int w1 = (unsigned int)f2bf(lrelu(a.z)) | ((unsigned int)f2bf(lrelu(a.w)) << 16);
        unsigned int w2 = (unsigned int)f2bf(lrelu(b.x)) | ((unsigned int)f2bf(lrelu(b.y)) << 16);
        unsigned int w3 = (unsigned int)f2bf(lrelu(b.z)) | ((unsigned int)f2bf(lrelu(b.w)) << 16);
        uint4 o = make_uint4(w0, w1, w2, w3);
        np[q] = o;       // n0 half (bf16)
        np[4 + q] = o;   // n half (n == n0 initially)
    }
    float4 z = make_float4(0.f, 0.f, 0.f, 0.f);
    float4* sp = (float4*)(s + (size_t)i * 16);
    sp[0] = z; sp[1] = z; sp[2] = z; sp[3] = z;
    cnt[i] = 0.f;
}

// ---- encoder MLP 6->18->18->16 (lrelu each); e0 (f32) -> slot 4 of out; in-degree ----
__global__ void __launch_bounds__(256) encoder(const float* __restrict__ ea,
                                               const int* __restrict__ eidx,
                                               const int* __restrict__ flags,
                                               const float* __restrict__ wsW,
                                               float* __restrict__ outbase,
                                               float* __restrict__ cnt) {
    int e = blockIdx.x * 256 + threadIdx.x;  // E % 256 == 0
    const float* ap = ea + (size_t)e * 6;
    float a[6];
#pragma unroll
    for (int k = 0; k < 6; k++) a[k] = ap[k];

    float h1[18];
#pragma unroll
    for (int j = 0; j < 18; j++) h1[j] = wsW[O_ENCB0 + j];
#pragma unroll
    for (int k = 0; k < 6; k++) {
        float v = a[k];
#pragma unroll
        for (int j = 0; j < 18; j++) h1[j] = fmaf(v, wsW[O_ENCW0 + k * 18 + j], h1[j]);
    }
#pragma unroll
    for (int j = 0; j < 18; j++) h1[j] = lrelu(h1[j]);

    float h2[18];
#pragma unroll
    for (int j = 0; j < 18; j++) h2[j] = wsW[O_ENCB1 + j];
#pragma unroll
    for (int k = 0; k < 18; k++) {
        float v = h1[k];
#pragma unroll
        for (int j = 0; j < 18; j++) h2[j] = fmaf(v, wsW[O_ENCW1 + k * 18 + j], h2[j]);
    }
#pragma unroll
    for (int j = 0; j < 18; j++) h2[j] = lrelu(h2[j]);

    float o[16];
#pragma unroll
    for (int j = 0; j < 16; j++) o[j] = wsW[O_ENCB2 + j];
#pragma unroll
    for (int k = 0; k < 18; k++) {
        float v = h2[k];
#pragma unroll
        for (int j = 0; j < 16; j++) o[j] = fmaf(v, wsW[O_ENCW2 + k * 16 + j], o[j]);
    }
    float4* ow = (float4*)(outbase + (size_t)4 * N_EDGES * 16 + (size_t)e * 16);
#pragma unroll
    for (int q = 0; q < 4; q++)
        ow[q] = make_float4(lrelu(o[4 * q]), lrelu(o[4 * q + 1]),
                            lrelu(o[4 * q + 2]), lrelu(o[4 * q + 3]));
    atomicAdd(&cnt[load_r(eidx, flags[0], e)], 1.0f);
}

// ---- edge update (round-3 structure; bf16 LDS staging for 2x occupancy) ----
// eh = [nc[row](64), nc[col](64), e0(16), eprev(16)] -> 80 (lrelu) -> 16 (lrelu)
// One wave per block; lane == local edge. sl stride 66 u16 (132 B):
// k-loop read bank = (33*lane + k/2) mod 32 -> lanes l, l+32 alias 2-way (free).
// e0/eprev are f32 in out-slots; staged bf16 into own sl row (fresh quantize per step).
template <int DO_ATOMICS>
__global__ void __launch_bounds__(64, 4) edge_step(const unsigned short* __restrict__ ncb,
                                                   const float* outb_c,
                                                   int slot_e0, int slot_prev, int slot_cur,
                                                   const int* __restrict__ eidx,
                                                   const int* __restrict__ flags,
                                                   const float* __restrict__ wsW,
                                                   float* __restrict__ s,
                                                   float* outb) {
    __shared__ unsigned short sl[64 * 66];   // 8448 B
    const int lane = threadIdx.x;
    const int e = blockIdx.x * 64 + lane;
    const float* W0 = wsW + O_EDGEW0;
    const float* b0 = wsW + O_EDGEB0;
    const float* W1 = wsW + O_EDGEW1;
    const float* b1 = wsW + O_EDGEB1;

    int r, c;
    load_rc(eidx, flags[0], e, r, c);

    float acc[80];
#pragma unroll
    for (int q = 0; q < 20; q++) {
        float4 b = ((const float4*)b0)[q];
        acc[4 * q] = b.x; acc[4 * q + 1] = b.y; acc[4 * q + 2] = b.z; acc[4 * q + 3] = b.w;
    }

#pragma unroll 1
    for (int pass = 0; pass < 2; pass++) {
        int idx = pass ? c : r;
        // cooperative gather: 64 lanes stage one 64-u16 nc row per iteration
#pragma unroll 8
        for (int e2 = 0; e2 < 64; e2++) {
            int node = __shfl(idx, e2, 64);
            sl[e2 * 66 + lane] = ncb[(size_t)node * 64 + lane];
        }
        __syncthreads();
        const float* Wp = W0 + (size_t)pass * 64 * 80;
        for (int k = 0; k < 64; k++) {
            float v = bf2f((unsigned int)sl[lane * 66 + k]);
            const float4* w = (const float4*)(Wp + k * 80);
#pragma unroll
            for (int q = 0; q < 20; q++) {
                float4 wv = w[q];
                acc[4 * q]     = fmaf(v, wv.x, acc[4 * q]);
                acc[4 * q + 1] = fmaf(v, wv.y, acc[4 * q + 1]);
                acc[4 * q + 2] = fmaf(v, wv.z, acc[4 * q + 2]);
                acc[4 * q + 3] = fmaf(v, wv.w, acc[4 * q + 3]);
            }
        }
        __syncthreads();
    }

    // load own e0 (f32, k rows 128..143) + eprev (f32, rows 144..159);
    // stage bf16 into own sl row (same-thread RW, no barrier needed)
    {
        const float4* e0p = (const float4*)(outb_c + (size_t)slot_e0 * N_EDGES * 16 + (size_t)e * 16);
        const float4* epp = (const float4*)(outb_c + (size_t)slot_prev * N_EDGES * 16 + (size_t)e * 16);
        float4 ev[8];
#pragma unroll
        for (int q = 0; q < 4; q++) ev[q] = e0p[q];
#pragma unroll
        for (int q = 0; q < 4; q++) ev[4 + q] = epp[q];
        unsigned int* sl32 = (unsigned int*)sl;
        int b32 = lane * 33;
#pragma unroll
        for (int q = 0; q < 8; q++) {
            sl32[b32 + 2 * q] =
                (unsigned int)f2bf(ev[q].x) | ((unsigned int)f2bf(ev[q].y) << 16);
            sl32[b32 + 2 * q + 1] =
                (unsigned int)f2bf(ev[q].z) | ((unsigned int)f2bf(ev[q].w) << 16);
        }
    }
    for (int k = 0; k < 32; k++) {
        float v = bf2f((unsigned int)sl[lane * 66 + k]);
        const float4* w = (const float4*)(W0 + (128 + k) * 80);
#pragma unroll
        for (int q = 0; q < 20; q++) {
            float4 wv = w[q];
            acc[4 * q]     = fmaf(v, wv.x, acc[4 * q]);
            acc[4 * q + 1] = fmaf(v, wv.y, acc[4 * q + 1]);
            acc[4 * q + 2] = fmaf(v, wv.z, acc[4 * q + 2]);
            acc[4 * q + 3] = fmaf(v, wv.w, acc[4 * q + 3]);
        }
    }

    // layer 2: 80 -> 16 (fully unrolled: static acc indices)
    float o[16];
#pragma unroll
    for (int q = 0; q < 4; q++) {
        float4 b = ((const float4*)b1)[q];
        o[4 * q] = b.x; o[4 * q + 1] = b.y; o[4 * q + 2] = b.z; o[4 * q + 3] = b.w;
    }
#pragma unroll
    for (int j = 0; j < 80; j++) {
        float v = lrelu(acc[j]);
        const float4* w = (const float4*)(W1 + j * 16);
#pragma unroll
        for (int q = 0; q < 4; q++) {
            float4 wv = w[q];
            o[4 * q]     = fmaf(v, wv.x, o[4 * q]);
            o[4 * q + 1] = fmaf(v, wv.y, o[4 * q + 1]);
            o[4 * q + 2] = fmaf(v, wv.z, o[4 * q + 2]);
            o[4 * q + 3] = fmaf(v, wv.w, o[4 * q + 3]);
        }
    }
    float act[16];
#pragma unroll
    for (int q = 0; q < 16; q++) act[q] = lrelu(o[q]);

    float4* ow = (float4*)(outb + (size_t)slot_cur * N_EDGES * 16 + (size_t)e * 16);
#pragma unroll
    for (int q = 0; q < 4; q++)
        ow[q] = make_float4(act[4 * q], act[4 * q + 1], act[4 * q + 2], act[4 * q + 3]);
    if (DO_ATOMICS) {
#pragma unroll
        for (int q = 0; q < 16; q++) atomicAdd(&s[(size_t)r * 16 + q], act[q]);
    }
}

// ---- node update: nh=[nc(bf16->f32), s/max(cnt,1)] (80) -> 56 (relu) -> 32 (relu) ----
__global__ void __launch_bounds__(64) node_step(float* __restrict__ s,
                                                const float* __restrict__ cnt,
                                                unsigned short* __restrict__ ncb,
                                                const float* __restrict__ wsW) {
    __shared__ float sl[64 * 81];
    const int l = threadIdx.x;
    const int i = blockIdx.x * 64 + l;
    if (i >= N_NODES) return;
    const float* W0 = wsW + O_NODEW0;
    const float* b0 = wsW + O_NODEB0;
    const float* W1 = wsW + O_NODEW1;
    const float* b1 = wsW + O_NODEB1;

    const uint4* ncp = (const uint4*)(ncb + (size_t)i * 64);
#pragma unroll
    for (int q = 0; q < 8; q++) {
        uint4 u = ncp[q];
        int base = l * 81 + 8 * q;
        sl[base + 0] = bf2f(u.x & 0xffffu); sl[base + 1] = bf2f(u.x >> 16);
        sl[base + 2] = bf2f(u.y & 0xffffu); sl[base + 3] = bf2f(u.y >> 16);
        sl[base + 4] = bf2f(u.z & 0xffffu); sl[base + 5] = bf2f(u.z >> 16);
        sl[base + 6] = bf2f(u.w & 0xffffu); sl[base + 7] = bf2f(u.w >> 16);
    }
    float inv = 1.0f / fmaxf(cnt[i], 1.0f);
    float4* sp = (float4*)(s + (size_t)i * 16);
    float4 z = make_float4(0.f, 0.f, 0.f, 0.f);
#pragma unroll
    for (int q = 0; q < 4; q++) {
        float4 v = sp[q];
        int base = l * 81 + 64 + 4 * q;
        sl[base] = v.x * inv; sl[base + 1] = v.y * inv;
        sl[base + 2] = v.z * inv; sl[base + 3] = v.w * inv;
        sp[q] = z;  // reset accumulator for the next step
    }

    float h[56];
#pragma unroll
    for (int q = 0; q < 14; q++) {
        float4 b = ((const float4*)b0)[q];
        h[4 * q] = b.x; h[4 * q + 1] = b.y; h[4 * q + 2] = b.z; h[4 * q + 3] = b.w;
    }
    for (int k = 0; k < 80; k++) {
        float v = sl[l * 81 + k];
        const float4* w = (const float4*)(W0 + k * 56);
#pragma unroll
        for (int q = 0; q < 14; q++) {
            float4 wv = w[q];
            h[4 * q]     = fmaf(v, wv.x, h[4 * q]);
            h[4 * q + 1] = fmaf(v, wv.y, h[4 * q + 1]);
            h[4 * q + 2] = fmaf(v, wv.z, h[4 * q + 2]);
            h[4 * q + 3] = fmaf(v, wv.w, h[4 * q + 3]);
        }
    }
#pragma unroll
    for (int j = 0; j < 56; j++) sl[l * 81 + j] = fmaxf(h[j], 0.f);

    float o[32];
#pragma unroll
    for (int q = 0; q < 8; q++) {
        float4 b = ((const float4*)b1)[q];
        o[4 * q] = b.x; o[4 * q + 1] = b.y; o[4 * q + 2] = b.z; o[4 * q + 3] = b.w;
    }
    for (int j = 0; j < 56; j++) {
        float v = sl[l * 81 + j];
        const float4* w = (const float4*)(W1 + j * 32);
#pragma unroll
        for (int q = 0; q < 8; q++) {
            float4 wv = w[q];
            o[4 * q]     = fmaf(v, wv.x, o[4 * q]);
            o[4 * q + 1] = fmaf(v, wv.y, o[4 * q + 1]);
            o[4 * q + 2] = fmaf(v, wv.z, o[4 * q + 2]);
            o[4 * q + 3] = fmaf(v, wv.w, o[4 * q + 3]);
        }
    }
    // write n half back as bf16
    uint4* nout = (uint4*)(ncb + (size_t)i * 64 + 32);
#pragma unroll
    for (int q = 0; q < 4; q++) {
        unsigned int w0 = (unsigned int)f2bf(fmaxf(o[8 * q + 0], 0.f)) |
                          ((unsigned int)f2bf(fmaxf(o[8 * q + 1], 0.f)) << 16);
        unsigned int w1 = (unsigned int)f2bf(fmaxf(o[8 * q + 2], 0.f)) |
                          ((unsigned int)f2bf(fmaxf(o[8 * q + 3], 0.f)) << 16);
        unsigned int w2 = (unsigned int)f2bf(fmaxf(o[8 * q + 4], 0.f)) |
                          ((unsigned int)f2bf(fmaxf(o[8 * q + 5], 0.f)) << 16);
        unsigned int w3 = (unsigned int)f2bf(fmaxf(o[8 * q + 6], 0.f)) |
                          ((unsigned int)f2bf(fmaxf(o[8 * q + 7], 0.f)) << 16);
        nout[q] = make_uint4(w0, w1, w2, w3);
    }
}

extern "C" void kernel_launch(void* const* d_in, const int* in_sizes, int n_in,
                              void* d_out, int out_size, void* d_ws, size_t ws_size,
                              hipStream_t stream) {
    (void)in_sizes; (void)n_in; (void)out_size;
    const float* x  = (const float*)d_in[0];
    const int* eidx = (const int*)d_in[1];
    const float* ea = (const float*)d_in[2];
    float* out = (float*)d_out;   // f32 output: 5 slots x E x 16

    // d_ws layout (float units): s[800000] | cnt[50000] | wsW[21308] | flags[4] | ncb (u16, 3.2M)
    float* wsf = (float*)d_ws;
    float* s   = wsf;
    float* cnt = wsf + 800000;
    float* wsW = wsf + 850000;
    int* flags = (int*)(wsf + 850000 + W_TOTAL);            // float idx 871308
    unsigned short* ncb = (unsigned short*)(wsf + 871312);  // byte 3,485,248 (16B aligned)
    const size_t WS_NEEDED = 3485248ull + 6400000ull;
    if (ws_size < WS_NEEDED) return;  // refuse to corrupt memory

    WPack P;
    static const int offs[15] = {0, 108, 126, 450, 468, 756, 772, 13572, 13652,
                                 14932, 14948, 19428, 19484, 21276, 21308};
    for (int a = 0; a < 14; a++) P.p[a] = (const float*)d_in[3 + a];
    for (int a = 0; a < 15; a++) P.off[a] = offs[a];

    detect_flags<<<1, 64, 0, stream>>>(eidx, flags);
    copy_w<<<14, 256, 0, stream>>>(P, wsW);
    init_nodes<<<196, 256, 0, stream>>>(x, ncb, s, cnt);
    encoder<<<N_EDGES / 256, 256, 0, stream>>>(ea, eidx, flags, wsW, out, cnt);

    // e-history in f32 d_out slots; final out[j] = e_{j+2}
    // t=1: e0(s4)->s0; t=2: s0->s0; t=3: s0->s1; t=4: s1->s2; t=5: s2->s3; t=6: s3->s4
    // every overlap is a same-thread read-before-write on a private 64B row
    const int prevs[6] = {4, 0, 0, 1, 2, 3};
    const int curs[6]  = {0, 0, 1, 2, 3, 4};

    for (int t = 1; t <= 6; t++) {
        if (t < 6)
            edge_step<1><<<N_EDGES / 64, 64, 0, stream>>>(ncb, out, 4, prevs[t - 1],
                                                          curs[t - 1], eidx, flags, wsW,
                                                          s, out);
        else
            edge_step<0><<<N_EDGES / 64, 64, 0, stream>>>(ncb, out, 4, prevs[t - 1],
                                                          curs[t - 1], eidx, flags, wsW,
                                                          s, out);
        if (t < 6)
            node_step<<<782, 64, 0, stream>>>(s, cnt, ncb, wsW);
    }
}

// Round 9
// 3207.958 us; speedup vs baseline: 2.8474x; 2.5036x over previous
//
#include <hip/hip_runtime.h>

#define N_NODES 50000
#define N_EDGES 1600000

// weight offsets (floats) inside the weights region of d_ws
#define O_ENCW0 0
#define O_ENCB0 108
#define O_ENCW1 126
#define O_ENCB1 450
#define O_ENCW2 468
#define O_ENCB2 756
#define O_EDGEW0 772
#define O_EDGEB0 13572
#define O_EDGEW1 13652
#define O_EDGEB1 14932
#define O_NODEW0 14948
#define O_NODEB0 19428
#define O_NODEW1 19484
#define O_NODEB1 21276
#define W_TOTAL 21308

typedef __attribute__((ext_vector_type(8))) short bf16x8;
typedef __attribute__((ext_vector_type(4))) float f32x4;

__device__ __forceinline__ float bf2f(unsigned int u) {
    return __uint_as_float(u << 16);
}
__device__ __forceinline__ unsigned short f2bf(float f) {
    unsigned int u = __float_as_uint(f);
    u += 0x7fffu + ((u >> 16) & 1u);   // RNE (finite values only here)
    return (unsigned short)(u >> 16);
}
__device__ __forceinline__ float lrelu(float x) { return x > 0.f ? x : 0.01f * x; }

__device__ __forceinline__ bf16x8 pack8(float4 a, float4 b) {
    bf16x8 r;
    r[0] = (short)f2bf(a.x); r[1] = (short)f2bf(a.y);
    r[2] = (short)f2bf(a.z); r[3] = (short)f2bf(a.w);
    r[4] = (short)f2bf(b.x); r[5] = (short)f2bf(b.y);
    r[6] = (short)f2bf(b.z); r[7] = (short)f2bf(b.w);
    return r;
}

struct WPack {
    const float* p[14];
    int off[15];
};

// ---- detect flag: edge_index is int64 (high words of first 64 entries all zero) ----
__global__ void detect_flags(const int* __restrict__ eidx, int* __restrict__ flags) {
    int t = threadIdx.x;  // 64 threads
    int v = eidx[2 * t + 1];
    unsigned long long bi = __ballot(v != 0);
    if (t == 0) flags[0] = (bi == 0ull) ? 1 : 0;
}

__device__ __forceinline__ void load_rc(const int* eidx, int flag64, int e, int& r, int& c) {
    if (flag64) {
        const long long* e64 = (const long long*)eidx;
        r = (int)e64[e];
        c = (int)e64[N_EDGES + e];
    } else {
        r = eidx[e];
        c = eidx[N_EDGES + e];
    }
}
__device__ __forceinline__ int load_r(const int* eidx, int flag64, int e) {
    return flag64 ? (int)((const long long*)eidx)[e] : eidx[e];
}

// ---- copy all f32 weight/bias arrays into contiguous ws region ----
__global__ void copy_w(WPack P, float* __restrict__ dst) {
    int a = blockIdx.x;
    const float* s = P.p[a];
    int n = P.off[a + 1] - P.off[a];
    float* d = dst + P.off[a];
    for (int i = threadIdx.x; i < n; i += 256) d[i] = s[i];
}

// ---- build transposed bf16 W0 for MFMA B-fragments ----
// wT[col*160 + k] = bf16(W0[k][col]);  W0 f32 [160][80] row-major
__global__ void build_wT(const float* __restrict__ w0,
                         unsigned short* __restrict__ wT) {
    int t = blockIdx.x * 256 + threadIdx.x;  // 50 * 256 = 12800
    if (t < 12800) {
        int col = t / 160, k = t % 160;
        wT[t] = f2bf(w0[k * 80 + col]);
    }
}

// ---- n0 = lrelu(x) (f32 in) stored bf16; ncb = [n0, n0]; zero s, cnt ----
__global__ void __launch_bounds__(256) init_nodes(const float* __restrict__ x,
                                                  unsigned short* __restrict__ ncb,
                                                  float* __restrict__ s,
                                                  float* __restrict__ cnt) {
    int i = blockIdx.x * 256 + threadIdx.x;
    if (i >= N_NODES) return;
    const float4* xin = (const float4*)(x + (size_t)i * 32);  // 8 float4
    uint4* np = (uint4*)(ncb + (size_t)i * 64);
#pragma unroll
    for (int q = 0; q < 4; q++) {
        float4 a = xin[2 * q];
        float4 b = xin[2 * q + 1];
        unsigned int w0 = (unsigned int)f2bf(lrelu(a.x)) | ((unsigned int)f2bf(lrelu(a.y)) << 16);
        unsigned int w1 = (unsigned int)f2bf(lrelu(a.z)) | ((unsigned int)f2bf(lrelu(a.w)) << 16);
        unsigned int w2 = (unsigned int)f2bf(lrelu(b.x)) | ((unsigned int)f2bf(lrelu(b.y)) << 16);
        unsigned int w3 = (unsigned int)f2bf(lrelu(b.z)) | ((unsigned int)f2bf(lrelu(b.w)) << 16);
        uint4 o = make_uint4(w0, w1, w2, w3);
        np[q] = o;       // n0 half (bf16)
        np[4 + q] = o;   // n half (n == n0 initially)
    }
    float4 z = make_float4(0.f, 0.f, 0.f, 0.f);
    float4* sp = (float4*)(s + (size_t)i * 16);
    sp[0] = z; sp[1] = z; sp[2] = z; sp[3] = z;
    cnt[i] = 0.f;
}

// ---- encoder MLP 6->18->18->16 (lrelu each); e0 (f32) -> slot 4 of out; in-degree ----
__global__ void __launch_bounds__(256) encoder(const float* __restrict__ ea,
                                               const int* __restrict__ eidx,
                                               const int* __restrict__ flags,
                                               const float* __restrict__ wsW,
                                               float* __restrict__ outbase,
                                               float* __restrict__ cnt) {
    int e = blockIdx.x * 256 + threadIdx.x;  // E % 256 == 0
    const float* ap = ea + (size_t)e * 6;
    float a[6];
#pragma unroll
    for (int k = 0; k < 6; k++) a[k] = ap[k];

    float h1[18];
#pragma unroll
    for (int j = 0; j < 18; j++) h1[j] = wsW[O_ENCB0 + j];
#pragma unroll
    for (int k = 0; k < 6; k++) {
        float v = a[k];
#pragma unroll
        for (int j = 0; j < 18; j++) h1[j] = fmaf(v, wsW[O_ENCW0 + k * 18 + j], h1[j]);
    }
#pragma unroll
    for (int j = 0; j < 18; j++) h1[j] = lrelu(h1[j]);

    float h2[18];
#pragma unroll
    for (int j = 0; j < 18; j++) h2[j] = wsW[O_ENCB1 + j];
#pragma unroll
    for (int k = 0; k < 18; k++) {
        float v = h1[k];
#pragma unroll
        for (int j = 0; j < 18; j++) h2[j] = fmaf(v, wsW[O_ENCW1 + k * 18 + j], h2[j]);
    }
#pragma unroll
    for (int j = 0; j < 18; j++) h2[j] = lrelu(h2[j]);

    float o[16];
#pragma unroll
    for (int j = 0; j < 16; j++) o[j] = wsW[O_ENCB2 + j];
#pragma unroll
    for (int k = 0; k < 18; k++) {
        float v = h2[k];
#pragma unroll
        for (int j = 0; j < 16; j++) o[j] = fmaf(v, wsW[O_ENCW2 + k * 16 + j], o[j]);
    }
    float4* ow = (float4*)(outbase + (size_t)4 * N_EDGES * 16 + (size_t)e * 16);
#pragma unroll
    for (int q = 0; q < 4; q++)
        ow[q] = make_float4(lrelu(o[4 * q]), lrelu(o[4 * q + 1]),
                            lrelu(o[4 * q + 2]), lrelu(o[4 * q + 3]));
    atomicAdd(&cnt[load_r(eidx, flags[0], e)], 1.0f);
}

// ---- edge update: layer1 (160->80) on MFMA; layer2 (80->16) on f32 VALU ----
// 256 thr = 4 waves; wave owns 16 edges (A-rows); block owns 64 edges.
// eh k-layout: [0,64)=nc[row], [64,128)=nc[col], [128,144)=e0, [144,160)=eprev
// MFMA 16x16x32 frags: A row = lane&15, k = st*32 + (lane>>4)*8 + j (contig 8/lane);
// B col = lane&15, same k (wT[col*160+k]); D col = lane&15, row = 4*(lane>>4)+reg.
// All e-prev reads feed layer-1 MFMAs (pre-barrier); out writes are post-barrier ->
// in-place slot step is race-free.
template <int DO_ATOMICS>
__global__ void __launch_bounds__(256) edge_mfma(const unsigned short* __restrict__ ncb,
                                                 const float* __restrict__ outb_c,
                                                 int slot_e0, int slot_prev, int slot_cur,
                                                 const int* __restrict__ eidx,
                                                 const int* __restrict__ flags,
                                                 const float* __restrict__ wsW,
                                                 const unsigned short* __restrict__ wT,
                                                 float* __restrict__ s,
                                                 float* __restrict__ outb) {
    __shared__ float act1f[64][84];  // 21.5 KB; rows 16B-aligned; 2-way alias only
    const int lane = threadIdx.x & 63;
    const int wave = threadIdx.x >> 6;
    const int r16 = lane & 15;
    const int g = lane >> 4;
    const int flag64 = flags[0];

    const int el = blockIdx.x * 64 + wave * 16 + r16;   // this lane's A-row edge
    int r_el, c_el;
    load_rc(eidx, flag64, el, r_el, c_el);

    // ---- gather A-fragments (bf16x8 per K-step) ----
    bf16x8 a[5];
    a[0] = *(const bf16x8*)(ncb + (size_t)r_el * 64 + g * 8);
    a[1] = *(const bf16x8*)(ncb + (size_t)r_el * 64 + 32 + g * 8);
    a[2] = *(const bf16x8*)(ncb + (size_t)c_el * 64 + g * 8);
    a[3] = *(const bf16x8*)(ncb + (size_t)c_el * 64 + 32 + g * 8);
    {
        const float* src = (g < 2) ? (outb_c + (size_t)slot_e0 * N_EDGES * 16)
                                   : (outb_c + (size_t)slot_prev * N_EDGES * 16);
        const float4* p = (const float4*)(src + (size_t)el * 16 + (g & 1) * 8);
        a[4] = pack8(p[0], p[1]);
    }

    // ---- layer 1: 5 N-tiles x 16 cols, K=160 (5 MFMA each), lrelu -> f32 LDS ----
#pragma unroll
    for (int t = 0; t < 5; t++) {
        float bv = wsW[O_EDGEB0 + t * 16 + r16];
        f32x4 acc = {bv, bv, bv, bv};
#pragma unroll
        for (int st = 0; st < 5; st++) {
            bf16x8 b = *(const bf16x8*)(wT + (t * 16 + r16) * 160 + st * 32 + g * 8);
            acc = __builtin_amdgcn_mfma_f32_16x16x32_bf16(a[st], b, acc, 0, 0, 0);
        }
#pragma unroll
        for (int i = 0; i < 4; i++)
            act1f[wave * 16 + g * 4 + i][t * 16 + r16] = lrelu(acc[i]);
    }
    __syncthreads();

    // ---- layer 2: f32 VALU. thread -> (edge eL = tid>>2, cols j0 = (tid&3)*4..+3) ----
    const int tid = threadIdx.x;
    const int eL = tid >> 2;
    const int j0 = (tid & 3) * 4;
    float o[4];
    {
        float4 bv = *(const float4*)(wsW + O_EDGEB1 + j0);
        o[0] = bv.x; o[1] = bv.y; o[2] = bv.z; o[3] = bv.w;
    }
#pragma unroll
    for (int k4 = 0; k4 < 20; k4++) {
        float4 v4 = *(const float4*)&act1f[eL][k4 * 4];
        const float* wr = wsW + O_EDGEW1 + k4 * 64 + j0;   // W1 f32 [80][16] row-major
        float4 wa = *(const float4*)(wr);
        float4 wb = *(const float4*)(wr + 16);
        float4 wc = *(const float4*)(wr + 32);
        float4 wd = *(const float4*)(wr + 48);
        o[0] = fmaf(v4.x, wa.x, o[0]); o[1] = fmaf(v4.x, wa.y, o[1]);
        o[2] = fmaf(v4.x, wa.z, o[2]); o[3] = fmaf(v4.x, wa.w, o[3]);
        o[0] = fmaf(v4.y, wb.x, o[0]); o[1] = fmaf(v4.y, wb.y, o[1]);
        o[2] = fmaf(v4.y, wb.z, o[2]); o[3] = fmaf(v4.y, wb.w, o[3]);
        o[0] = fmaf(v4.z, wc.x, o[0]); o[1] = fmaf(v4.z, wc.y, o[1]);
        o[2] = fmaf(v4.z, wc.z, o[2]); o[3] = fmaf(v4.z, wc.w, o[3]);
        o[0] = fmaf(v4.w, wd.x, o[0]); o[1] = fmaf(v4.w, wd.y, o[1]);
        o[2] = fmaf(v4.w, wd.z, o[2]); o[3] = fmaf(v4.w, wd.w, o[3]);
    }
    float act[4];
#pragma unroll
    for (int jj = 0; jj < 4; jj++) act[jj] = lrelu(o[jj]);

    const int eg = blockIdx.x * 64 + eL;
    float4* ow = (float4*)(outb + (size_t)slot_cur * N_EDGES * 16 + (size_t)eg * 16 + j0);
    *ow = make_float4(act[0], act[1], act[2], act[3]);

    if (DO_ATOMICS) {
        int rg = load_r(eidx, flag64, eg);
#pragma unroll
        for (int jj = 0; jj < 4; jj++)
            atomicAdd(&s[(size_t)rg * 16 + j0 + jj], act[jj]);
    }
}

// ---- node update: nh=[nc(bf16->f32), s/max(cnt,1)] (80) -> 56 (relu) -> 32 (relu) ----
__global__ void __launch_bounds__(64) node_step(float* __restrict__ s,
                                                const float* __restrict__ cnt,
                                                unsigned short* __restrict__ ncb,
                                                const float* __restrict__ wsW) {
    __shared__ float sl[64 * 81];
    const int l = threadIdx.x;
    const int i = blockIdx.x * 64 + l;
    if (i >= N_NODES) return;
    const float* W0 = wsW + O_NODEW0;
    const float* b0 = wsW + O_NODEB0;
    const float* W1 = wsW + O_NODEW1;
    const float* b1 = wsW + O_NODEB1;

    const uint4* ncp = (const uint4*)(ncb + (size_t)i * 64);
#pragma unroll
    for (int q = 0; q < 8; q++) {
        uint4 u = ncp[q];
        int base = l * 81 + 8 * q;
        sl[base + 0] = bf2f(u.x & 0xffffu); sl[base + 1] = bf2f(u.x >> 16);
        sl[base + 2] = bf2f(u.y & 0xffffu); sl[base + 3] = bf2f(u.y >> 16);
        sl[base + 4] = bf2f(u.z & 0xffffu); sl[base + 5] = bf2f(u.z >> 16);
        sl[base + 6] = bf2f(u.w & 0xffffu); sl[base + 7] = bf2f(u.w >> 16);
    }
    float inv = 1.0f / fmaxf(cnt[i], 1.0f);
    float4* sp = (float4*)(s + (size_t)i * 16);
    float4 z = make_float4(0.f, 0.f, 0.f, 0.f);
#pragma unroll
    for (int q = 0; q < 4; q++) {
        float4 v = sp[q];
        int base = l * 81 + 64 + 4 * q;
        sl[base] = v.x * inv; sl[base + 1] = v.y * inv;
        sl[base + 2] = v.z * inv; sl[base + 3] = v.w * inv;
        sp[q] = z;  // reset accumulator for the next step
    }

    float h[56];
#pragma unroll
    for (int q = 0; q < 14; q++) {
        float4 b = ((const float4*)b0)[q];
        h[4 * q] = b.x; h[4 * q + 1] = b.y; h[4 * q + 2] = b.z; h[4 * q + 3] = b.w;
    }
    for (int k = 0; k < 80; k++) {
        float v = sl[l * 81 + k];
        const float4* w = (const float4*)(W0 + k * 56);
#pragma unroll
        for (int q = 0; q < 14; q++) {
            float4 wv = w[q];
            h[4 * q]     = fmaf(v, wv.x, h[4 * q]);
            h[4 * q + 1] = fmaf(v, wv.y, h[4 * q + 1]);
            h[4 * q + 2] = fmaf(v, wv.z, h[4 * q + 2]);
            h[4 * q + 3] = fmaf(v, wv.w, h[4 * q + 3]);
        }
    }
#pragma unroll
    for (int j = 0; j < 56; j++) sl[l * 81 + j] = fmaxf(h[j], 0.f);

    float o[32];
#pragma unroll
    for (int q = 0; q < 8; q++) {
        float4 b = ((const float4*)b1)[q];
        o[4 * q] = b.x; o[4 * q + 1] = b.y; o[4 * q + 2] = b.z; o[4 * q + 3] = b.w;
    }
    for (int j = 0; j < 56; j++) {
        float v = sl[l * 81 + j];
        const float4* w = (const float4*)(W1 + j * 32);
#pragma unroll
        for (int q = 0; q < 8; q++) {
            float4 wv = w[q];
            o[4 * q]     = fmaf(v, wv.x, o[4 * q]);
            o[4 * q + 1] = fmaf(v, wv.y, o[4 * q + 1]);
            o[4 * q + 2] = fmaf(v, wv.z, o[4 * q + 2]);
            o[4 * q + 3] = fmaf(v, wv.w, o[4 * q + 3]);
        }
    }
    // write n half back as bf16
    uint4* nout = (uint4*)(ncb + (size_t)i * 64 + 32);
#pragma unroll
    for (int q = 0; q < 4; q++) {
        unsigned int w0 = (unsigned int)f2bf(fmaxf(o[8 * q + 0], 0.f)) |
                          ((unsigned int)f2bf(fmaxf(o[8 * q + 1], 0.f)) << 16);
        unsigned int w1 = (unsigned int)f2bf(fmaxf(o[8 * q + 2], 0.f)) |
                          ((unsigned int)f2bf(fmaxf(o[8 * q + 3], 0.f)) << 16);
        unsigned int w2 = (unsigned int)f2bf(fmaxf(o[8 * q + 4], 0.f)) |
                          ((unsigned int)f2bf(fmaxf(o[8 * q + 5], 0.f)) << 16);
        unsigned int w3 = (unsigned int)f2bf(fmaxf(o[8 * q + 6], 0.f)) |
                          ((unsigned int)f2bf(fmaxf(o[8 * q + 7], 0.f)) << 16);
        nout[q] = make_uint4(w0, w1, w2, w3);
    }
}

extern "C" void kernel_launch(void* const* d_in, const int* in_sizes, int n_in,
                              void* d_out, int out_size, void* d_ws, size_t ws_size,
                              hipStream_t stream) {
    (void)in_sizes; (void)n_in; (void)out_size;
    const float* x  = (const float*)d_in[0];
    const int* eidx = (const int*)d_in[1];
    const float* ea = (const float*)d_in[2];
    float* out = (float*)d_out;   // f32 output: 5 slots x E x 16

    // d_ws layout (float units): s[800000] | cnt[50000] | wsW[21308] | flags[4]
    //                            | ncb (u16, 3.2M) | wT (u16, 12800)
    float* wsf = (float*)d_ws;
    float* s   = wsf;
    float* cnt = wsf + 800000;
    float* wsW = wsf + 850000;
    int* flags = (int*)(wsf + 850000 + W_TOTAL);            // float idx 871308
    unsigned short* ncb = (unsigned short*)(wsf + 871312);  // byte 3,485,248 (16B aligned)
    unsigned short* wT  = ncb + (size_t)N_NODES * 64;       // + 6.4 MB
    const size_t WS_NEEDED = 3485248ull + 6400000ull + 25600ull;
    if (ws_size < WS_NEEDED) return;  // refuse to corrupt memory

    WPack P;
    static const int offs[15] = {0, 108, 126, 450, 468, 756, 772, 13572, 13652,
                                 14932, 14948, 19428, 19484, 21276, 21308};
    for (int a = 0; a < 14; a++) P.p[a] = (const float*)d_in[3 + a];
    for (int a = 0; a < 15; a++) P.off[a] = offs[a];

    detect_flags<<<1, 64, 0, stream>>>(eidx, flags);
    copy_w<<<14, 256, 0, stream>>>(P, wsW);
    build_wT<<<50, 256, 0, stream>>>((const float*)d_in[9], wT);
    init_nodes<<<196, 256, 0, stream>>>(x, ncb, s, cnt);
    encoder<<<N_EDGES / 256, 256, 0, stream>>>(ea, eidx, flags, wsW, out, cnt);

    // e-history in f32 d_out slots; final out[j] = e_{j+2}
    // t=1: e0(s4)->s0; t=2: s0->s0; t=3: s0->s1; t=4: s1->s2; t=5: s2->s3; t=6: s3->s4
    const int prevs[6] = {4, 0, 0, 1, 2, 3};
    const int curs[6]  = {0, 0, 1, 2, 3, 4};

    for (int t = 1; t <= 6; t++) {
        if (t < 6)
            edge_mfma<1><<<N_EDGES / 64, 256, 0, stream>>>(ncb, out, 4, prevs[t - 1],
                                                           curs[t - 1], eidx, flags, wsW,
                                                           wT, s, out);
        else
            edge_mfma<0><<<N_EDGES / 64, 256, 0, stream>>>(ncb, out, 4, prevs[t - 1],
                                                           curs[t - 1], eidx, flags, wsW,
                                                           wT, s, out);
        if (t < 6)
            node_step<<<782, 64, 0, stream>>>(s, cnt, ncb, wsW);
    }
}